// Round 3
// baseline (694.696 us; speedup 1.0000x reference)
//
#include <hip/hip_runtime.h>
#include <stdint.h>

#define N_NODES  20000
#define N_EDGES  200000
#define N_SEG    16
#define EXTENT   32
#define N_PATHS  64
#define OP_SIZE  (N_SEG * EXTENT)   // 512
#define MAXT     33   // worst-case record PAIRS per group stream (K1e+K2e <= 64 -> 32, +1 margin)

// s_waitcnt imm (gfx9): vmcnt[3:0]=b3:0, expcnt=b6:4, lgkmcnt=b11:8, vmcnt[5:4]=b15:14
#define WAIT_VM0  0x0F70   // vmcnt(0), lgkm/exp no-wait
#define WAIT_VM4  0x0F74   // vmcnt(4), lgkm/exp no-wait

// ---------------- CSR build ----------------

__global__ void k_hist(const int* __restrict__ dst, int* __restrict__ offsets) {
    int e = blockIdx.x * blockDim.x + threadIdx.x;
    if (e < N_EDGES) atomicAdd(&offsets[dst[e]], 1);
}

// single block, 1024 threads, LDS-staged exclusive scan (coalesced global I/O)
__global__ __launch_bounds__(1024) void k_scan(int* __restrict__ offsets) {
    __shared__ int buf[N_NODES];     // 80 KB
    __shared__ int wsum[16];
    const int tid = threadIdx.x;
    for (int i = tid; i < N_NODES; i += 1024) buf[i] = offsets[i];
    __syncthreads();
    const int C = (N_NODES + 1023) / 1024;   // 20
    int lo = tid * C;
    int hi = lo + C; if (hi > N_NODES) hi = N_NODES; if (lo > N_NODES) lo = N_NODES;
    int s = 0;
    for (int i = lo; i < hi; ++i) s += buf[i];
    const int lane = tid & 63, w = tid >> 6;
    int v = s;
    for (int d = 1; d < 64; d <<= 1) { int t = __shfl_up(v, d); if (lane >= d) v += t; }
    if (lane == 63) wsum[w] = v;
    __syncthreads();
    int wpre = 0;
    for (int q = 0; q < w; ++q) wpre += wsum[q];
    int acc = wpre + v - s;
    for (int i = lo; i < hi; ++i) { int t = buf[i]; buf[i] = acc; acc += t; }
    __syncthreads();
    for (int i = tid; i < N_NODES; i += 1024) offsets[i] = buf[i];
}

// after scatter, offsets[n] == end(n); start(n) = offsets[n-1], start(0) = 0
__global__ void k_scatter(const int* __restrict__ dst, const int* __restrict__ src,
                          int* __restrict__ offsets, int2* __restrict__ el2) {
    int e = blockIdx.x * blockDim.x + threadIdx.x;
    if (e < N_EDGES) {
        int pos = atomicAdd(&offsets[dst[e]], 1);
        el2[pos] = make_int2(e, src[e]);   // {edge id, src node}
    }
}

// ---------------- path table ----------------
// G=8 groups of 8 lanes; each lane covers 4 columns (float4 / ds_read_b128).
// Segs sorted by path-count desc; snake assignment: group g owns seg order[g]
// (slot 0) and seg order[15-g] (slot 1).  Per-edge iteration count =
// c1 + c9 (max count + 9th-largest) instead of sum of pair maxima (~36 -> ~14).
// Record stream per group, consumed in PAIRS via one broadcast ds_read_b128:
//   tab[kk*8 + g] = int4{ packA, coefA, packB, coefB }
//   pack = (bytesX1 << 16) | bytesX2;  bytesX1 = i1*128, bytesX2 = 2048 + i2*128
// Slot 0 occupies pairs [0, p1), slot 1 pairs [p1, p2); both slots padded to
// even record count; pad records = {2048, 0.0f} (valid addrs, zero coef).
__global__ void k_paths(const int* __restrict__ pi, const float* __restrict__ pc,
                        int* __restrict__ ks2g, int4* __restrict__ recg,
                        int* __restrict__ segmap) {
    __shared__ int   s_i1[N_PATHS], s_i2[N_PATHS], s_i3[N_PATHS];
    __shared__ float s_c[N_PATHS];
    __shared__ int4  s_rec[MAXT * 8];   // 4224 B
    const int p = threadIdx.x;   // 64 threads
    s_i1[p] = pi[3 * p]; s_i2[p] = pi[3 * p + 1]; s_i3[p] = pi[3 * p + 2];
    s_c[p]  = pc[p];
    for (int q = p; q < MAXT * 8; q += 64) s_rec[q] = make_int4(2048, 0, 2048, 0);
    __syncthreads();
    if (p == 0) {
        int cnt[N_SEG];
        for (int s = 0; s < N_SEG; ++s) cnt[s] = 0;
        for (int q = 0; q < N_PATHS; ++q) cnt[s_i3[q]]++;
        int order[N_SEG];
        for (int s = 0; s < N_SEG; ++s) order[s] = s;
        for (int a = 1; a < N_SEG; ++a) {           // insertion sort, count desc
            int o = order[a], b = a;
            while (b > 0 && cnt[order[b - 1]] < cnt[o]) { order[b] = order[b - 1]; --b; }
            order[b] = o;
        }
        const int K1 = cnt[order[0]], K2 = cnt[order[8]];
        const int K1e = K1 + (K1 & 1), K2e = K2 + (K2 & 1);
        const int p1 = K1e >> 1, p2 = (K1e + K2e) >> 1;
        for (int g = 0; g < 8; ++g) {
            const int sA = order[g], sB = order[15 - g];
            segmap[g] = sA; segmap[8 + g] = sB;
            int w = 0;                                 // slot 0 stream
            for (int q = 0; q < N_PATHS; ++q) if (s_i3[q] == sA) {
                int pk = ((s_i1[q] * 128) << 16) | (2048 + s_i2[q] * 128);
                int* r = (int*)&s_rec[(w >> 1) * 8 + g];
                if (w & 1) { r[2] = pk; r[3] = __float_as_int(s_c[q]); }
                else       { r[0] = pk; r[1] = __float_as_int(s_c[q]); }
                ++w;
            }
            w = K1e;                                   // slot 1 stream
            for (int q = 0; q < N_PATHS; ++q) if (s_i3[q] == sB) {
                int pk = ((s_i1[q] * 128) << 16) | (2048 + s_i2[q] * 128);
                int* r = (int*)&s_rec[(w >> 1) * 8 + g];
                if (w & 1) { r[2] = pk; r[3] = __float_as_int(s_c[q]); }
                else       { r[0] = pk; r[1] = __float_as_int(s_c[q]); }
                ++w;
            }
        }
        ks2g[0] = p1; ks2g[1] = p2;
    }
    __syncthreads();
    for (int q = p; q < MAXT * 8; q += 64) recg[q] = s_rec[q];
}

// ---------------- main: 1 wave/node, 1 edge/iter, 2-deep pipelined ----------------

__device__ __forceinline__ void async16(const float* g, float* l) {
    // per-lane 16B global -> wave-uniform LDS base + lane*16
    __builtin_amdgcn_global_load_lds(
        (const __attribute__((address_space(1))) uint32_t*)g,
        (__attribute__((address_space(3))) uint32_t*)l, 16, 0, 0);
}

__device__ __forceinline__ void stage(const float* __restrict__ x_nodes,
                                      const float* __restrict__ x_edges,
                                      int2 m, float* l, int lane) {
    const float* gn = x_nodes + (size_t)m.y * OP_SIZE + lane * 4;
    const float* ge = x_edges + (size_t)m.x * OP_SIZE + lane * 4;
    async16(gn,       l);
    async16(gn + 256, l + 256);
    async16(ge,       l + 512);
    async16(ge + 256, l + 768);
}

__global__ __launch_bounds__(64, 5) void k_main(
    const float* __restrict__ x_nodes, const float* __restrict__ x_edges,
    const int* __restrict__ offsets, const int2* __restrict__ el2,
    const int* __restrict__ ks2g, const int4* __restrict__ recg,
    const int* __restrict__ segmap, float* __restrict__ out)
{
    __shared__ float lds[2 * 1024];   // 2 sets x (x1 row 512 | x2 row 512) = 8 KB
    __shared__ int4  tab[MAXT * 8];   // 4224 B, 16B-aligned

    const int lane = threadIdx.x;     // 0..63
    const int li   = lane & 7;        // lane-in-group: columns 4*li .. 4*li+3
    const int g    = lane >> 3;       // group 0..7
    const int n    = blockIdx.x;

    const int p1 = ks2g[0], p2 = ks2g[1];

    // stage the (runtime-sized) table into LDS once per block
    for (int q = lane; q < p2 * 8; q += 64) tab[q] = recg[q];

    const int segA = segmap[g], segB = segmap[8 + g];

    const int start = (n == 0) ? 0 : offsets[n - 1];
    const int end   = offsets[n];
    const int deg   = end - start;

    float a0x = 0.f, a0y = 0.f, a0z = 0.f, a0w = 0.f;   // slot-0 seg accumulator
    float a1x = 0.f, a1y = 0.f, a1z = 0.f, a1w = 0.f;   // slot-1 seg accumulator

    __syncthreads();   // drains tab global-loads + ds_writes before staging begins

    // prologue: issue edges 0 and 1, prefetch meta for edge 2
    int2 mq = make_int2(0, 0);
    if (deg > 0) stage(x_nodes, x_edges, el2[start],     lds,        lane);
    if (deg > 1) stage(x_nodes, x_edges, el2[start + 1], lds + 1024, lane);
    if (deg > 2) mq = el2[start + 2];

    for (int i = 0; i < deg; ++i) {
        // prefetch meta for edge i+3 (uniform -> scalar load path)
        int2 mf = make_int2(0, 0);
        if (i + 3 < deg) mf = el2[start + i + 3];

        // edge i's 4 staging loads are the oldest outstanding; leave edge i+1's in flight
        if (i + 1 < deg) __builtin_amdgcn_s_waitcnt(WAIT_VM4);
        else             __builtin_amdgcn_s_waitcnt(WAIT_VM0);
        __builtin_amdgcn_sched_barrier(0);

        // buffer-relative byte base: buffer toggle + lane column (16B per lane)
        const char* base = (const char*)lds + ((i & 1) << 12) + (li << 4);

        for (int kk = 0; kk < p1; ++kk) {             // slot 0 -> a0
            int4 q = tab[kk * 8 + g];                 // 2 records, broadcast b128
            const float4 u0 = *(const float4*)(base + (q.x >> 16));
            const float4 v0 = *(const float4*)(base + (q.x & 0xffff));
            const float  c0 = __int_as_float(q.y);
            a0x = fmaf(c0, u0.x * v0.x, a0x);
            a0y = fmaf(c0, u0.y * v0.y, a0y);
            a0z = fmaf(c0, u0.z * v0.z, a0z);
            a0w = fmaf(c0, u0.w * v0.w, a0w);
            const float4 u1 = *(const float4*)(base + (q.z >> 16));
            const float4 v1 = *(const float4*)(base + (q.z & 0xffff));
            const float  c1 = __int_as_float(q.w);
            a0x = fmaf(c1, u1.x * v1.x, a0x);
            a0y = fmaf(c1, u1.y * v1.y, a0y);
            a0z = fmaf(c1, u1.z * v1.z, a0z);
            a0w = fmaf(c1, u1.w * v1.w, a0w);
        }
        for (int kk = p1; kk < p2; ++kk) {            // slot 1 -> a1
            int4 q = tab[kk * 8 + g];
            const float4 u0 = *(const float4*)(base + (q.x >> 16));
            const float4 v0 = *(const float4*)(base + (q.x & 0xffff));
            const float  c0 = __int_as_float(q.y);
            a1x = fmaf(c0, u0.x * v0.x, a1x);
            a1y = fmaf(c0, u0.y * v0.y, a1y);
            a1z = fmaf(c0, u0.z * v0.z, a1z);
            a1w = fmaf(c0, u0.w * v0.w, a1w);
            const float4 u1 = *(const float4*)(base + (q.z >> 16));
            const float4 v1 = *(const float4*)(base + (q.z & 0xffff));
            const float  c1 = __int_as_float(q.w);
            a1x = fmaf(c1, u1.x * v1.x, a1x);
            a1y = fmaf(c1, u1.y * v1.y, a1y);
            a1z = fmaf(c1, u1.z * v1.z, a1z);
            a1w = fmaf(c1, u1.w * v1.w, a1w);
        }

        // overwrite this set with edge i+2 (ds_reads above already executed;
        // DMA arrival is >> LDS-pipe depth, no hazard)
        if (i + 2 < deg) {
            stage(x_nodes, x_edges, mq, lds + ((i & 1) << 10), lane);
            mq = mf;
        }
    }

    float* row = out + (size_t)n * OP_SIZE;
    *(float4*)(row + segA * EXTENT + li * 4) = make_float4(a0x, a0y, a0z, a0w);
    *(float4*)(row + segB * EXTENT + li * 4) = make_float4(a1x, a1y, a1z, a1w);
}

// ---------------- launch ----------------

extern "C" void kernel_launch(void* const* d_in, const int* in_sizes, int n_in,
                              void* d_out, int out_size, void* d_ws, size_t ws_size,
                              hipStream_t stream) {
    const float* x_nodes      = (const float*)d_in[0];
    const float* x_edges      = (const float*)d_in[1];
    const float* path_coeffs  = (const float*)d_in[2];
    const int*   src          = (const int*)d_in[3];
    const int*   dst          = (const int*)d_in[4];
    const int*   path_indices = (const int*)d_in[5];
    float* out = (float*)d_out;

    char* ws = (char*)d_ws;
    int*  offsets = (int*)ws;                          ws += N_NODES * sizeof(int);    // 80000
    int2* el2     = (int2*)ws;                         ws += N_EDGES * sizeof(int2);   // 1.6 MB
    int4* recg    = (int4*)ws;                         ws += MAXT * 8 * sizeof(int4);  // 4224
    int*  ks2g    = (int*)ws;                          ws += 16 * sizeof(int);
    int*  segmap  = (int*)ws;

    hipMemsetAsync(offsets, 0, N_NODES * sizeof(int), stream);
    k_hist   <<<(N_EDGES + 255) / 256, 256, 0, stream>>>(dst, offsets);
    k_scan   <<<1, 1024, 0, stream>>>(offsets);
    k_scatter<<<(N_EDGES + 255) / 256, 256, 0, stream>>>(dst, src, offsets, el2);
    k_paths  <<<1, 64, 0, stream>>>(path_indices, path_coeffs, ks2g, recg, segmap);
    k_main   <<<N_NODES, 64, 0, stream>>>(x_nodes, x_edges, offsets, el2,
                                          ks2g, recg, segmap, out);
}